// Round 4
// 2604.397 us; speedup vs baseline: 1.7498x; 1.7498x over previous
//
#include <hip/hip_runtime.h>

#define TSTEPS 2048
#define NENV   256
#define HID    128
#define EPB    16                 // envs per block (= MFMA M)
#define NBLK   (NENV / EPB)       // 16 blocks for the scan
#define NTHREADS 512              // 8 waves; wave w owns h-dims [16w,16w+16)

// gi layout: [t][gate][envblk][j][16 envs] fp32  (1KB-contiguous per (gate,envblk,wave))
#define GI_EB_STRIDE (HID * EPB)                  // 2048 elems
#define GI_G_STRIDE  (NBLK * GI_EB_STRIDE)        // 32768 elems
#define GI_T_STRIDE  (3 * GI_G_STRIDE)            // 98304 elems
#define GI_BYTES   ((size_t)TSTEPS * GI_T_STRIDE * sizeof(float))   // 805 MB

typedef float          floatx4  __attribute__((ext_vector_type(4)));
typedef __bf16         bf16x8   __attribute__((ext_vector_type(8)));
typedef unsigned short ushortx8 __attribute__((ext_vector_type(8)));
typedef unsigned int   uintx4   __attribute__((ext_vector_type(4)));

// fp32 -> bf16 round-to-nearest-even (scalar fallback)
__device__ __forceinline__ unsigned short f2bf(float f) {
    unsigned u = __float_as_uint(f);
    u += 0x7FFFu + ((u >> 16) & 1u);
    return (unsigned short)(u >> 16);
}

// packed fp32x2 -> bf16x2 (gfx950 v_cvt_pk_bf16_f32 when available)
__device__ __forceinline__ unsigned cvt_pk_bf16(float a, float b) {
#if __has_builtin(__builtin_amdgcn_cvt_pk_bf16_f32)
    typedef __bf16 bf16x2 __attribute__((ext_vector_type(2)));
    bf16x2 r = __builtin_amdgcn_cvt_pk_bf16_f32(a, b);
    return __builtin_bit_cast(unsigned, r);
#else
    return (unsigned)f2bf(a) | ((unsigned)f2bf(b) << 16);
#endif
}

__device__ __forceinline__ bf16x8 pack8(floatx4 a, floatx4 b) {
    uintx4 u;
    u[0] = cvt_pk_bf16(a[0], a[1]);
    u[1] = cvt_pk_bf16(a[2], a[3]);
    u[2] = cvt_pk_bf16(b[0], b[1]);
    u[3] = cvt_pk_bf16(b[2], b[3]);
    return __builtin_bit_cast(bf16x8, u);
}

__device__ __forceinline__ float fast_rcp(float x) {
#if __has_builtin(__builtin_amdgcn_rcpf)
    return __builtin_amdgcn_rcpf(x);
#else
    return 1.0f / x;
#endif
}
__device__ __forceinline__ float sigm(float x) {
    return fast_rcp(1.0f + __expf(-x));
}
__device__ __forceinline__ float tanh_fast(float x) {
    return 1.0f - 2.0f * fast_rcp(1.0f + __expf(2.0f * x));
}

// ---------------------------------------------------------------------------
// Phase 1: gi[t][g][eb][j][e] = x[t*N+eb*16+e][:] . w_ih[g*128+j][:] + b_ih[g*128+j]
// Grid: 2048 blocks = (tc 0..127) x (eb 0..15), 512 threads.
// ---------------------------------------------------------------------------
__global__ __launch_bounds__(NTHREADS, 2)
void gi_gemm(const float* __restrict__ x,
             const float* __restrict__ w_ih,
             const float* __restrict__ b_ih,
             float* __restrict__ gi)
{
    const int tid  = threadIdx.x;
    const int wv   = tid >> 6;
    const int lane = tid & 63;
    const int quad = lane >> 4;
    const int l15  = lane & 15;
    const int eb   = blockIdx.x & 15;      // env group
    const int tc   = blockIdx.x >> 4;      // t chunk (16 steps)
    const int j    = wv * 16 + l15;        // within-gate output column

    // B-frags: w_ih columns for this wave's j, all 3 gates
    bf16x8 bI[3][4];
    float bias[3];
#pragma unroll
    for (int q = 0; q < 3; ++q) {
        const int col = q * HID + j;
        bias[q] = b_ih[col];
#pragma unroll
        for (int kk = 0; kk < 4; ++kk) {
            const int kb = kk * 32 + quad * 8;
            floatx4 f0 = *(const floatx4*)(w_ih + col * HID + kb);
            floatx4 f1 = *(const floatx4*)(w_ih + col * HID + kb + 4);
            bI[q][kk] = pack8(f0, f1);
        }
    }

    for (int tt = 0; tt < 16; ++tt) {
        const int t = tc * 16 + tt;
        // A-frag: x rows (16 envs), lane row = env l15, k = kk*32+quad*8
        const float* xr = x + (size_t)(t * NENV + eb * EPB + l15) * HID;
        bf16x8 ax[4];
#pragma unroll
        for (int kk = 0; kk < 4; ++kk) {
            const int kb = kk * 32 + quad * 8;
            floatx4 f0 = *(const floatx4*)(xr + kb);
            floatx4 f1 = *(const floatx4*)(xr + kb + 4);
            ax[kk] = pack8(f0, f1);
        }
        floatx4 acc[3];
#pragma unroll
        for (int q = 0; q < 3; ++q) { acc[q][0] = acc[q][1] = acc[q][2] = acc[q][3] = bias[q]; }
#pragma unroll
        for (int kk = 0; kk < 4; ++kk) {
            acc[0] = __builtin_amdgcn_mfma_f32_16x16x32_bf16(ax[kk], bI[0][kk], acc[0], 0, 0, 0);
            acc[1] = __builtin_amdgcn_mfma_f32_16x16x32_bf16(ax[kk], bI[1][kk], acc[1], 0, 0, 0);
            acc[2] = __builtin_amdgcn_mfma_f32_16x16x32_bf16(ax[kk], bI[2][kk], acc[2], 0, 0, 0);
        }
        // C layout: rows = quad*4+i = env (within eb), col l15 part of j.
        // gi layout => one 1KB-contiguous slab per (gate, wave).
#pragma unroll
        for (int q = 0; q < 3; ++q) {
            float* dst = gi + (size_t)t * GI_T_STRIDE + q * GI_G_STRIDE
                            + eb * GI_EB_STRIDE + j * EPB + quad * 4;
            *(floatx4*)dst = acc[q];
        }
    }
}

// ---------------------------------------------------------------------------
// Phase 2: sequential scan, h-side only. 16 blocks x 512 threads.
// Raw s_barrier + lgkmcnt-only fence: gi/mask prefetches and out-stores stay
// in flight across the barrier (counted vmcnt at use), unlike __syncthreads
// which drains vmcnt(0) every step.
// ---------------------------------------------------------------------------
__global__ __launch_bounds__(NTHREADS, 2)
void gru_scan(const float* __restrict__ gi,
              const float* __restrict__ h0,
              const float* __restrict__ masks,
              const float* __restrict__ w_hh,
              const float* __restrict__ b_hh,
              float* __restrict__ out)
{
    __shared__ unsigned short hbuf[2][EPB][136];   // +8 pad breaks bank conflicts

    const int tid  = threadIdx.x;
    const int wv   = tid >> 6;
    const int lane = tid & 63;
    const int quad = lane >> 4;
    const int l15  = lane & 15;
    const int envbase = blockIdx.x * EPB;
    const int j = wv * 16 + l15;

    // B-frags for w_hh only (48 VGPRs)
    bf16x8 bH[3][4];
#pragma unroll
    for (int q = 0; q < 3; ++q) {
        const int col = q * HID + j;
#pragma unroll
        for (int kk = 0; kk < 4; ++kk) {
            const int kb = kk * 32 + quad * 8;
            floatx4 g0 = *(const floatx4*)(w_hh + col * HID + kb);
            floatx4 g1 = *(const floatx4*)(w_hh + col * HID + kb + 4);
            bH[q][kk] = pack8(g0, g1);
        }
    }

    const float biasR  = b_hh[j];
    const float biasZ  = b_hh[HID + j];
    const float biasNH = b_hh[2 * HID + j];

    // init h (apply mask_0), C-layout: rows = envs quad*4+i, col j
    float hC[4];
    {
        floatx4 m0 = *(const floatx4*)(masks + envbase + quad * 4);
#pragma unroll
        for (int i = 0; i < 4; ++i) {
            const int e = quad * 4 + i;
            float h = h0[(envbase + e) * HID + j] * m0[i];
            hC[i] = h;
            hbuf[0][e][j] = f2bf(h);
        }
    }

    // gi base for this lane: + t*GI_T_STRIDE + g*GI_G_STRIDE
    const float* gbase = gi + (size_t)blockIdx.x * GI_EB_STRIDE
                            + (size_t)j * EPB + quad * 4;

    // depth-2 software pipeline: gA/gB hold gi[t], gi[t+1]; mA/mB hold
    // mask(t+1), mask(t+2) (mask(t+1) is consumed at the END of step t).
    floatx4 gA[3], gB[3];
#pragma unroll
    for (int g = 0; g < 3; ++g) {
        gA[g] = *(const floatx4*)(gbase + g * GI_G_STRIDE);
        gB[g] = *(const floatx4*)(gbase + GI_T_STRIDE + g * GI_G_STRIDE);
    }
    floatx4 mA = *(const floatx4*)(masks + (size_t)1 * NENV + envbase + quad * 4);
    floatx4 mB = *(const floatx4*)(masks + (size_t)2 * NENV + envbase + quad * 4);

    float* const outs = out;
    float* const hfin = out + (size_t)TSTEPS * NENV * HID;

    auto step = [&](int t, int p, floatx4 (&gc)[3], floatx4& mreg) {
        // hbuf[p^1] writes must be visible to all waves; LDS-only drain,
        // global loads/stores stay outstanding across the barrier.
        asm volatile("s_waitcnt lgkmcnt(0)" ::: "memory");
        __builtin_amdgcn_s_barrier();
        __builtin_amdgcn_sched_barrier(0);

        // A-frags for h from LDS
        bf16x8 ah[4];
#pragma unroll
        for (int kk = 0; kk < 4; ++kk) {
            ah[kk] = __builtin_bit_cast(bf16x8,
                *(const ushortx8*)&hbuf[p][l15][kk * 32 + quad * 8]);
        }

        // consume gc into accumulators now, freeing gc regs for t+2 prefetch
        floatx4 accR, accZ, accNH, gN;
#pragma unroll
        for (int i = 0; i < 4; ++i) {
            accR[i]  = gc[0][i] + biasR;
            accZ[i]  = gc[1][i] + biasZ;
            gN[i]    = gc[2][i];
            accNH[i] = biasNH;
        }

        // prefetch gi[t+2] into the same registers (~2 steps of slack)
        if (t + 2 < TSTEPS) {
            const float* gp = gbase + (size_t)(t + 2) * GI_T_STRIDE;
#pragma unroll
            for (int g = 0; g < 3; ++g) gc[g] = *(const floatx4*)(gp + g * GI_G_STRIDE);
        }

        // mask(t+1) for this step's epilogue; reload mreg with mask(t+3)
        floatx4 mn = mreg;
        if (t + 3 < TSTEPS) {
            mreg = *(const floatx4*)(masks + (size_t)(t + 3) * NENV + envbase + quad * 4);
        } else {
            mreg[0] = mreg[1] = mreg[2] = mreg[3] = 1.0f;
        }

#pragma unroll
        for (int kk = 0; kk < 4; ++kk) {
            accR  = __builtin_amdgcn_mfma_f32_16x16x32_bf16(ah[kk], bH[0][kk], accR,  0, 0, 0);
            accZ  = __builtin_amdgcn_mfma_f32_16x16x32_bf16(ah[kk], bH[1][kk], accZ,  0, 0, 0);
            accNH = __builtin_amdgcn_mfma_f32_16x16x32_bf16(ah[kk], bH[2][kk], accNH, 0, 0, 0);
        }

#pragma unroll
        for (int i = 0; i < 4; ++i) {
            const int e = quad * 4 + i;
            float r    = sigm(accR[i]);
            float z    = sigm(accZ[i]);
            float n    = tanh_fast(gN[i] + r * accNH[i]);
            float hnew = n + z * (hC[i] - n);
            outs[((size_t)t * NENV + envbase + e) * HID + j] = hnew;
            if (t == TSTEPS - 1) hfin[(envbase + e) * HID + j] = hnew;
            float hm = hnew * mn[i];
            hC[i] = hm;
            hbuf[p ^ 1][e][j] = f2bf(hm);
        }
    };

    for (int t = 0; t < TSTEPS; t += 2) {
        step(t,     0, gA, mA);
        step(t + 1, 1, gB, mB);
    }
}

// ---------------------------------------------------------------------------
// Fallback: round-1 fused kernel (used only if ws_size < GI_BYTES)
// ---------------------------------------------------------------------------
__global__ __launch_bounds__(NTHREADS, 2)
void gru_fused(const float* __restrict__ x,
               const float* __restrict__ h0,
               const float* __restrict__ masks,
               const float* __restrict__ w_ih,
               const float* __restrict__ w_hh,
               const float* __restrict__ b_ih,
               const float* __restrict__ b_hh,
               float* __restrict__ out)
{
    __shared__ unsigned short hbuf[2][EPB][136];

    const int tid  = threadIdx.x;
    const int wv   = tid >> 6;
    const int lane = tid & 63;
    const int quad = lane >> 4;
    const int l15  = lane & 15;
    const int envbase = blockIdx.x * EPB;
    const int j = wv * 16 + l15;

    bf16x8 bI[3][4], bH[3][4];
#pragma unroll
    for (int q = 0; q < 3; ++q) {
        const int col = q * HID + j;
#pragma unroll
        for (int kk = 0; kk < 4; ++kk) {
            const int kb = kk * 32 + quad * 8;
            floatx4 f0 = *(const floatx4*)(w_ih + col * HID + kb);
            floatx4 f1 = *(const floatx4*)(w_ih + col * HID + kb + 4);
            bI[q][kk] = pack8(f0, f1);
            floatx4 g0 = *(const floatx4*)(w_hh + col * HID + kb);
            floatx4 g1 = *(const floatx4*)(w_hh + col * HID + kb + 4);
            bH[q][kk] = pack8(g0, g1);
        }
    }

    const float biasR  = b_ih[j]           + b_hh[j];
    const float biasZ  = b_ih[HID + j]     + b_hh[HID + j];
    const float biasNI = b_ih[2 * HID + j];
    const float biasNH = b_hh[2 * HID + j];

    float hC[4];
    {
        floatx4 m0 = *(const floatx4*)(masks + envbase + quad * 4);
#pragma unroll
        for (int i = 0; i < 4; ++i) {
            const int e = quad * 4 + i;
            float h = h0[(envbase + e) * HID + j] * m0[i];
            hC[i] = h;
            hbuf[0][e][j] = f2bf(h);
        }
    }

    floatx4 xA[8], xB[8];
    {
        const float* xr = x + (size_t)(envbase + l15) * HID;
#pragma unroll
        for (int kk = 0; kk < 4; ++kk) {
            const int kb = kk * 32 + quad * 8;
            xA[2 * kk]     = *(const floatx4*)(xr + kb);
            xA[2 * kk + 1] = *(const floatx4*)(xr + kb + 4);
        }
    }

    float* const outs = out;
    float* const hfin = out + (size_t)TSTEPS * NENV * HID;

    auto step = [&](int t, int p, floatx4 (&xc)[8], floatx4 (&xn)[8]) {
        __syncthreads();
        bf16x8 ah[4];
#pragma unroll
        for (int kk = 0; kk < 4; ++kk) {
            ah[kk] = __builtin_bit_cast(bf16x8,
                *(const ushortx8*)&hbuf[p][l15][kk * 32 + quad * 8]);
        }
        bf16x8 ax[4];
#pragma unroll
        for (int kk = 0; kk < 4; ++kk) ax[kk] = pack8(xc[2 * kk], xc[2 * kk + 1]);

        if (t + 1 < TSTEPS) {
            const float* xr = x + (size_t)((t + 1) * NENV + envbase + l15) * HID;
#pragma unroll
            for (int kk = 0; kk < 4; ++kk) {
                const int kb = kk * 32 + quad * 8;
                xn[2 * kk]     = *(const floatx4*)(xr + kb);
                xn[2 * kk + 1] = *(const floatx4*)(xr + kb + 4);
            }
        }
        floatx4 mn;
        if (t + 1 < TSTEPS) {
            mn = *(const floatx4*)(masks + (size_t)(t + 1) * NENV + envbase + quad * 4);
        } else {
            mn[0] = mn[1] = mn[2] = mn[3] = 1.0f;
        }

        floatx4 accR  = {biasR,  biasR,  biasR,  biasR};
        floatx4 accZ  = {biasZ,  biasZ,  biasZ,  biasZ};
        floatx4 accNI = {biasNI, biasNI, biasNI, biasNI};
        floatx4 accNH = {biasNH, biasNH, biasNH, biasNH};
#pragma unroll
        for (int kk = 0; kk < 4; ++kk) {
            accR  = __builtin_amdgcn_mfma_f32_16x16x32_bf16(ax[kk], bI[0][kk], accR,  0, 0, 0);
            accR  = __builtin_amdgcn_mfma_f32_16x16x32_bf16(ah[kk], bH[0][kk], accR,  0, 0, 0);
            accZ  = __builtin_amdgcn_mfma_f32_16x16x32_bf16(ax[kk], bI[1][kk], accZ,  0, 0, 0);
            accZ  = __builtin_amdgcn_mfma_f32_16x16x32_bf16(ah[kk], bH[1][kk], accZ,  0, 0, 0);
            accNI = __builtin_amdgcn_mfma_f32_16x16x32_bf16(ax[kk], bI[2][kk], accNI, 0, 0, 0);
            accNH = __builtin_amdgcn_mfma_f32_16x16x32_bf16(ah[kk], bH[2][kk], accNH, 0, 0, 0);
        }

#pragma unroll
        for (int i = 0; i < 4; ++i) {
            const int e = quad * 4 + i;
            float r    = sigm(accR[i]);
            float z    = sigm(accZ[i]);
            float n    = tanh_fast(accNI[i] + r * accNH[i]);
            float hnew = n + z * (hC[i] - n);
            outs[((size_t)t * NENV + envbase + e) * HID + j] = hnew;
            if (t == TSTEPS - 1) hfin[(envbase + e) * HID + j] = hnew;
            float hm = hnew * mn[i];
            hC[i] = hm;
            hbuf[p ^ 1][e][j] = f2bf(hm);
        }
    };

    for (int t = 0; t < TSTEPS; t += 2) {
        step(t,     0, xA, xB);
        step(t + 1, 1, xB, xA);
    }
}

extern "C" void kernel_launch(void* const* d_in, const int* in_sizes, int n_in,
                              void* d_out, int out_size, void* d_ws, size_t ws_size,
                              hipStream_t stream) {
    const float* x    = (const float*)d_in[0];
    const float* h0   = (const float*)d_in[1];
    const float* mks  = (const float*)d_in[2];
    const float* w_ih = (const float*)d_in[3];
    const float* w_hh = (const float*)d_in[4];
    const float* b_ih = (const float*)d_in[5];
    const float* b_hh = (const float*)d_in[6];
    (void)in_sizes; (void)n_in; (void)out_size;

    if (ws_size >= GI_BYTES) {
        float* gi = (float*)d_ws;
        gi_gemm<<<dim3(128 * 16), dim3(NTHREADS), 0, stream>>>(x, w_ih, b_ih, gi);
        gru_scan<<<dim3(NBLK), dim3(NTHREADS), 0, stream>>>(gi, h0, mks, w_hh, b_hh,
                                                            (float*)d_out);
    } else {
        gru_fused<<<dim3(NBLK), dim3(NTHREADS), 0, stream>>>(
            x, h0, mks, w_ih, w_hh, b_ih, b_hh, (float*)d_out);
    }
}